// Round 3
// baseline (202.710 us; speedup 1.0000x reference)
//
#include <hip/hip_runtime.h>
#include <hip/hip_bf16.h>
#include <cstdint>

#define L_DIM 4800
#define C_DIM 256
#define CONF_ELEMS ((size_t)2 * L_DIM * L_DIM)

typedef _Float16 f16x8 __attribute__((ext_vector_type(8)));
typedef float f32x4 __attribute__((ext_vector_type(4)));

typedef const __attribute__((address_space(1))) uint32_t glb_u32;
typedef __attribute__((address_space(3))) uint32_t lds_u32;

// ws layout (bytes):
//   rowsum  f32 [9600]   @ 0        (pass A: sums; after k_inv: 1/sum)
//   colsum  f32 [9600]   @ 38400
//   colmax  u32 [9600]   @ 76800
//   rowpack u64 [9600]   @ 115200
//   h0 f16 [2*4800*256]  @ 192000   (optional, if ws_size permits)
//   h1 f16 [2*4800*256]  @ 5107200  -> end 10022400

__global__ __launch_bounds__(256) void k_init(unsigned* ws) {
    int i = blockIdx.x * 256 + threadIdx.x;
    if (i < 48000) ws[i] = 0u;
}

// Fused: blocks [0,2400) convert f32->f16 (1200 per input); blocks [2400,2588) zero stats.
__global__ __launch_bounds__(256) void k_prep(const float* __restrict__ f0,
                                              const float* __restrict__ f1,
                                              _Float16* __restrict__ h0,
                                              _Float16* __restrict__ h1,
                                              unsigned* __restrict__ stats) {
    int b = blockIdx.x;
    if (b < 2400) {
        const float* src = (b < 1200) ? f0 : f1;
        _Float16* dst = (b < 1200) ? h0 : h1;
        int i = (b < 1200 ? b : b - 1200) * 256 + threadIdx.x;
        const float4* s4 = (const float4*)src;
        float4 a = s4[(size_t)i * 2], c = s4[(size_t)i * 2 + 1];
        f16x8 h = { (_Float16)a.x, (_Float16)a.y, (_Float16)a.z, (_Float16)a.w,
                    (_Float16)c.x, (_Float16)c.y, (_Float16)c.z, (_Float16)c.w };
        *(f16x8*)(dst + (size_t)i * 8) = h;
    } else {
        int i = (b - 2400) * 256 + threadIdx.x;
        if (i < 48000) stats[i] = 0u;
    }
}

__global__ __launch_bounds__(256) void k_inv(float* p) {
    int i = blockIdx.x * 256 + threadIdx.x;
    if (i < 19200) p[i] = 1.0f / p[i];
}

// 96x96 tile GEMM, BK=64, 4 waves (2x2), wave tile 48x48 (3x3 frags of 16x16x32 f16).
// 1D grid of 5000 blocks, XCD-aware decode: 5000 = 8 XCDs x 625 tiles, each XCD owns
// a contiguous y-band (per-XCD L2 working set ~3 MB < 4 MB -> panel re-reads L2-hit).
// LDS: [96 rows][8 chunks of 16B], slot kc8 holds k-chunk (kc8 ^ (row&7)) (T2 swizzle
// via pre-swizzled global source, both-sides rule 21).
template<bool F16SRC, bool FINAL>
__global__ __launch_bounds__(256) void k_gemm2(const void* __restrict__ srcA,
                                               const void* __restrict__ srcB,
                                               float* __restrict__ conf,
                                               float* __restrict__ rowsum,
                                               float* __restrict__ colsum,
                                               unsigned* __restrict__ colmax,
                                               unsigned long long* __restrict__ rowpack) {
    const int xcd = blockIdx.x & 7;
    const int idx = blockIdx.x >> 3;
    const int t   = xcd * 625 + idx;     // bijective: 5000 = 8*625
    const int n   = t / 2500;
    const int rem = t - n * 2500;
    const int ty  = rem / 50;
    const int tx  = rem - ty * 50;
    const int l0  = ty * 96;
    const int s0  = tx * 96;

    __shared__ __align__(16) _Float16 As[96 * 64];
    __shared__ __align__(16) _Float16 Bs[96 * 64];

    const int tid  = threadIdx.x;
    const int lane = tid & 63;
    const int w    = tid >> 6;
    const int wr   = w >> 1, wc = w & 1;
    const int q    = lane >> 4, r16 = lane & 15;

    f32x4 acc[3][3] = {};

    for (int kt = 0; kt < 4; ++kt) {
        const int k0 = kt * 64;
        __syncthreads();   // LDS reads of previous iter complete before overwrite
        if constexpr (F16SRC) {
            const _Float16* A = (const _Float16*)srcA + ((size_t)n * L_DIM + l0) * C_DIM;
            const _Float16* B = (const _Float16*)srcB + ((size_t)n * L_DIM + s0) * C_DIM;
#pragma unroll
            for (int i = 0; i < 3; ++i) {
                int c   = tid + i * 256;
                int row = c >> 3;
                int kc  = (c & 7) ^ (row & 7);    // pre-swizzled global source
                __builtin_amdgcn_global_load_lds(
                    (glb_u32*)(A + (size_t)row * C_DIM + k0 + kc * 8),
                    (lds_u32*)(As + (i * 256 + w * 64) * 8), 16, 0, 0);
                __builtin_amdgcn_global_load_lds(
                    (glb_u32*)(B + (size_t)row * C_DIM + k0 + kc * 8),
                    (lds_u32*)(Bs + (i * 256 + w * 64) * 8), 16, 0, 0);
            }
        } else {
            const float* A = (const float*)srcA + ((size_t)n * L_DIM + l0) * C_DIM;
            const float* B = (const float*)srcB + ((size_t)n * L_DIM + s0) * C_DIM;
#pragma unroll
            for (int i = 0; i < 3; ++i) {
                int c   = tid + i * 256;
                int row = c >> 3;
                int kc  = (c & 7) ^ (row & 7);
                const float* pa = A + (size_t)row * C_DIM + k0 + kc * 8;
                const float* pb = B + (size_t)row * C_DIM + k0 + kc * 8;
                float4 a0 = ((const float4*)pa)[0], a1 = ((const float4*)pa)[1];
                float4 b0 = ((const float4*)pb)[0], b1 = ((const float4*)pb)[1];
                f16x8 ha = { (_Float16)a0.x, (_Float16)a0.y, (_Float16)a0.z, (_Float16)a0.w,
                             (_Float16)a1.x, (_Float16)a1.y, (_Float16)a1.z, (_Float16)a1.w };
                f16x8 hb = { (_Float16)b0.x, (_Float16)b0.y, (_Float16)b0.z, (_Float16)b0.w,
                             (_Float16)b1.x, (_Float16)b1.y, (_Float16)b1.z, (_Float16)b1.w };
                *(f16x8*)(As + (size_t)c * 8) = ha;
                *(f16x8*)(Bs + (size_t)c * 8) = hb;
            }
        }
        __syncthreads();   // drains vmcnt(0): global_load_lds complete

        f16x8 af[2][3], bf[2][3];
#pragma unroll
        for (int m = 0; m < 3; ++m) {
            int row = wr * 48 + m * 16 + r16;
#pragma unroll
            for (int ks = 0; ks < 2; ++ks)
                af[ks][m] = *(const f16x8*)(As + row * 64 + (((ks * 4 + q) ^ (row & 7)) * 8));
        }
#pragma unroll
        for (int nn = 0; nn < 3; ++nn) {
            int row = wc * 48 + nn * 16 + r16;
#pragma unroll
            for (int ks = 0; ks < 2; ++ks)
                bf[ks][nn] = *(const f16x8*)(Bs + row * 64 + (((ks * 4 + q) ^ (row & 7)) * 8));
        }
#pragma unroll
        for (int ks = 0; ks < 2; ++ks)
#pragma unroll
            for (int m = 0; m < 3; ++m)
#pragma unroll
                for (int nn = 0; nn < 3; ++nn)
                    acc[m][nn] = __builtin_amdgcn_mfma_f32_16x16x32_f16(af[ks][m], bf[ks][nn], acc[m][nn], 0, 0, 0);
    }

    const float SIM_SCALE = 0.0390625f;  // (1/sqrt(C))^2 / TEMPERATURE

    if constexpr (!FINAL) {
        // Pass A: accumulate row/col sums of e = exp(sim)
        float cp[3] = {0.f, 0.f, 0.f};
#pragma unroll
        for (int m = 0; m < 3; ++m) {
#pragma unroll
            for (int reg = 0; reg < 4; ++reg) {
                float rsum = 0.f;
#pragma unroll
                for (int nn = 0; nn < 3; ++nn) {
                    float e = __expf(acc[m][nn][reg] * SIM_SCALE);
                    rsum += e;
                    cp[nn] += e;
                }
                rsum += __shfl_xor(rsum, 1);
                rsum += __shfl_xor(rsum, 2);
                rsum += __shfl_xor(rsum, 4);
                rsum += __shfl_xor(rsum, 8);
                if (r16 == 0)
                    atomicAdd(&rowsum[n * L_DIM + l0 + wr * 48 + m * 16 + q * 4 + reg], rsum);
            }
        }
#pragma unroll
        for (int nn = 0; nn < 3; ++nn) {
            float v = cp[nn];
            v += __shfl_xor(v, 16);
            v += __shfl_xor(v, 32);
            if (q == 0)
                atomicAdd(&colsum[n * L_DIM + s0 + wc * 48 + nn * 16 + r16], v);
        }
    } else {
        // Pass B: conf = exp(2*sim)*invR*invC -> write; fused row argmax / col max
        const size_t base = (size_t)n * L_DIM * L_DIM;
        float ivC[3];
#pragma unroll
        for (int nn = 0; nn < 3; ++nn)
            ivC[nn] = colsum[n * L_DIM + s0 + wc * 48 + nn * 16 + r16];
        float cmx[3] = {0.f, 0.f, 0.f};
#pragma unroll
        for (int m = 0; m < 3; ++m) {
#pragma unroll
            for (int reg = 0; reg < 4; ++reg) {
                const int grow = l0 + wr * 48 + m * 16 + q * 4 + reg;
                const float ivR = rowsum[n * L_DIM + grow];   // inverted by k_inv
                const size_t rowoff = base + (size_t)grow * L_DIM;
                float bv = -1.f; int bc = 0;
#pragma unroll
                for (int nn = 0; nn < 3; ++nn) {
                    const int gcol = s0 + wc * 48 + nn * 16 + r16;
                    float cf = __expf(acc[m][nn][reg] * (2.0f * SIM_SCALE)) * ivR * ivC[nn];
                    conf[rowoff + gcol] = cf;
                    cmx[nn] = fmaxf(cmx[nn], cf);
                    if (cf > bv) { bv = cf; bc = gcol; }
                }
                unsigned long long pack =
                    ((unsigned long long)__float_as_uint(bv) << 32) |
                    (unsigned long long)(0xFFFFFFFFu - (unsigned)bc);
#pragma unroll
                for (int d = 1; d < 16; d <<= 1) {
                    unsigned long long o = __shfl_xor(pack, d);
                    if (o > pack) pack = o;
                }
                if (r16 == 0)
                    atomicMax(&rowpack[n * L_DIM + grow], pack);
            }
        }
#pragma unroll
        for (int nn = 0; nn < 3; ++nn) {
            float v = cmx[nn];
            v = fmaxf(v, __shfl_xor(v, 16));
            v = fmaxf(v, __shfl_xor(v, 32));
            if (q == 0)
                atomicMax(&colmax[n * L_DIM + s0 + wc * 48 + nn * 16 + r16], __float_as_uint(v));
        }
    }
}

__global__ __launch_bounds__(256) void k_match(const unsigned long long* __restrict__ rowpack,
                                               const unsigned* __restrict__ colmax,
                                               float* __restrict__ out) {
    int i = blockIdx.x * 256 + threadIdx.x;
    if (i >= 2 * L_DIM) return;
    int n = i / L_DIM, l = i % L_DIM;
    unsigned long long p = rowpack[i];
    float v = __uint_as_float((unsigned)(p >> 32));
    int cand = (int)(0xFFFFFFFFu - (unsigned)(p & 0xFFFFFFFFull));
    if (cand < 0 || cand >= L_DIM) cand = 0;
    int h0 = l / 80, w0 = l % 80;
    int h1 = cand / 80, w1 = cand % 80;
    bool bm0 = (h0 >= 2) && (h0 < 58) && (w0 >= 2) && (w0 < 78);
    bool bm1 = (h1 >= 2) && (h1 < 58) && (w1 >= 2) && (w1 < 78);
    float cm = __uint_as_float(colmax[n * L_DIM + cand]);
    bool mask = (v > 0.2f) && bm0 && bm1 && (v == cm);
    out[CONF_ELEMS + i]         = mask ? 1.0f : 0.0f;        // mask_v
    out[CONF_ELEMS + 9600 + i]  = mask ? (float)cand : 0.0f; // j_ids
    out[CONF_ELEMS + 19200 + i] = mask ? v : 0.0f;           // mconf
}

extern "C" void kernel_launch(void* const* d_in, const int* in_sizes, int n_in,
                              void* d_out, int out_size, void* d_ws, size_t ws_size,
                              hipStream_t stream) {
    const float* f0 = (const float*)d_in[0];
    const float* f1 = (const float*)d_in[1];
    float* out = (float*)d_out;

    float* rowsum = (float*)d_ws;
    float* colsum = rowsum + 9600;
    unsigned* colmax = (unsigned*)(colsum + 9600);
    unsigned long long* rowpack = (unsigned long long*)((char*)d_ws + 115200);
    _Float16* h0 = (_Float16*)((char*)d_ws + 192000);
    _Float16* h1 = h0 + (size_t)2 * L_DIM * C_DIM;

    const bool usef16 = ws_size >= 10022400;

    if (usef16) {
        k_prep<<<dim3(2588), 256, 0, stream>>>(f0, f1, h0, h1, (unsigned*)d_ws);
        k_gemm2<true, false><<<dim3(5000), 256, 0, stream>>>(
            h0, h1, out, rowsum, colsum, colmax, rowpack);
        k_inv<<<dim3(75), 256, 0, stream>>>(rowsum);
        k_gemm2<true, true><<<dim3(5000), 256, 0, stream>>>(
            h0, h1, out, rowsum, colsum, colmax, rowpack);
    } else {
        k_init<<<dim3(188), 256, 0, stream>>>((unsigned*)d_ws);
        k_gemm2<false, false><<<dim3(5000), 256, 0, stream>>>(
            f0, f1, out, rowsum, colsum, colmax, rowpack);
        k_inv<<<dim3(75), 256, 0, stream>>>(rowsum);
        k_gemm2<false, true><<<dim3(5000), 256, 0, stream>>>(
            f0, f1, out, rowsum, colsum, colmax, rowpack);
    }
    k_match<<<dim3(38), 256, 0, stream>>>(rowpack, colmax, out);
}

// Round 4
// 132.684 us; speedup vs baseline: 1.5278x; 1.5278x over previous
//
#include <hip/hip_runtime.h>
#include <hip/hip_bf16.h>
#include <cstdint>

#define L_DIM 4800
#define C_DIM 256
#define CONF_ELEMS ((size_t)2 * L_DIM * L_DIM)

typedef _Float16 f16x8 __attribute__((ext_vector_type(8)));
typedef float f32x4 __attribute__((ext_vector_type(4)));

typedef const __attribute__((address_space(1))) uint32_t glb_u32;
typedef __attribute__((address_space(3))) uint32_t lds_u32;

// ws layout (bytes):
//   invsum  f32[19200]        @0         (1/rowsum | 1/colsum, by reduceA)
//   colmaxF u32[9600]         @76800     (by reduceB)
//   X region                  @115200:
//     pass A: partA f32[100][9600]  (slots 0..49 = row partial per tx, 50..99 = col partial per ty)
//     pass B: rowbest u64[50][9600] @115200 ; colbest u32[50][9600] @3955200
//   h0 f16 [2*4800*256]       @5875200   (f16 path only)
//   h1 f16 [2*4800*256]       @10790400  -> end 15705600
#define WS_F16_NEEDED 15705600

__global__ __launch_bounds__(256) void k_cvt2(const float* __restrict__ f0,
                                              const float* __restrict__ f1,
                                              _Float16* __restrict__ h0,
                                              _Float16* __restrict__ h1) {
    int b = blockIdx.x;
    const float* src = (b < 1200) ? f0 : f1;
    _Float16* dst = (b < 1200) ? h0 : h1;
    int i = (b < 1200 ? b : b - 1200) * 256 + threadIdx.x;
    const float4* s4 = (const float4*)src;
    float4 a = s4[(size_t)i * 2], c = s4[(size_t)i * 2 + 1];
    f16x8 h = { (_Float16)a.x, (_Float16)a.y, (_Float16)a.z, (_Float16)a.w,
                (_Float16)c.x, (_Float16)c.y, (_Float16)c.z, (_Float16)c.w };
    *(f16x8*)(dst + (size_t)i * 8) = h;
}

// invsum[i] = 1 / sum_k partA[(base+k)][j]   (rows: base 0; cols: base 50)
__global__ __launch_bounds__(256) void k_reduceA(const float* __restrict__ partA,
                                                 float* __restrict__ invsum) {
    int i = blockIdx.x * 256 + threadIdx.x;
    if (i >= 19200) return;
    int base = (i < 9600) ? 0 : 50;
    int j = (i < 9600) ? i : i - 9600;
    float s = 0.f;
#pragma unroll 10
    for (int k = 0; k < 50; ++k)
        s += partA[(size_t)(base + k) * 9600 + j];
    invsum[i] = 1.0f / s;
}

__global__ __launch_bounds__(256) void k_reduceB(const unsigned* __restrict__ colbest,
                                                 unsigned* __restrict__ colmaxF) {
    int i = blockIdx.x * 256 + threadIdx.x;
    if (i >= 9600) return;
    unsigned m = 0u;
#pragma unroll 10
    for (int k = 0; k < 50; ++k)
        m = max(m, colbest[(size_t)k * 9600 + i]);
    colmaxF[i] = m;
}

// 96x96 tile GEMM, BK=64, 4 waves (2x2), wave tile 48x48 (3x3 frags of 16x16x32 f16).
// 1D grid of 5000 blocks, XCD-aware decode (bijective: 5000 = 8*625).
// LDS: [96 rows][8 chunks of 16B], slot kc8 holds k-chunk (kc8 ^ (row&7)) (T2 both-sides).
// Epilogue: NO global atomics -- per-block LDS reduce, plain stores to per-slot scratch.
template<bool F16SRC, bool FINAL>
__global__ __launch_bounds__(256) void k_gemm2(const void* __restrict__ srcA,
                                               const void* __restrict__ srcB,
                                               float* __restrict__ conf,
                                               const float* __restrict__ invsum,
                                               float* __restrict__ partA,
                                               unsigned long long* __restrict__ rowbest,
                                               unsigned* __restrict__ colbest) {
    const int xcd = blockIdx.x & 7;
    const int idx = blockIdx.x >> 3;
    const int t   = xcd * 625 + idx;
    const int n   = t / 2500;
    const int rem = t - n * 2500;
    const int ty  = rem / 50;
    const int tx  = rem - ty * 50;
    const int l0  = ty * 96;
    const int s0  = tx * 96;

    __shared__ __align__(16) _Float16 As[96 * 64];
    __shared__ __align__(16) _Float16 Bs[96 * 64];
    __shared__ __align__(16) char redbuf[2304];

    const int tid  = threadIdx.x;
    const int lane = tid & 63;
    const int w    = tid >> 6;
    const int wr   = w >> 1, wc = w & 1;
    const int q    = lane >> 4, r16 = lane & 15;

    f32x4 acc[3][3] = {};

    for (int kt = 0; kt < 4; ++kt) {
        const int k0 = kt * 64;
        __syncthreads();
        if constexpr (F16SRC) {
            const _Float16* A = (const _Float16*)srcA + ((size_t)n * L_DIM + l0) * C_DIM;
            const _Float16* B = (const _Float16*)srcB + ((size_t)n * L_DIM + s0) * C_DIM;
#pragma unroll
            for (int i = 0; i < 3; ++i) {
                int c   = tid + i * 256;
                int row = c >> 3;
                int kc  = (c & 7) ^ (row & 7);
                __builtin_amdgcn_global_load_lds(
                    (glb_u32*)(A + (size_t)row * C_DIM + k0 + kc * 8),
                    (lds_u32*)(As + (i * 256 + w * 64) * 8), 16, 0, 0);
                __builtin_amdgcn_global_load_lds(
                    (glb_u32*)(B + (size_t)row * C_DIM + k0 + kc * 8),
                    (lds_u32*)(Bs + (i * 256 + w * 64) * 8), 16, 0, 0);
            }
        } else {
            const float* A = (const float*)srcA + ((size_t)n * L_DIM + l0) * C_DIM;
            const float* B = (const float*)srcB + ((size_t)n * L_DIM + s0) * C_DIM;
#pragma unroll
            for (int i = 0; i < 3; ++i) {
                int c   = tid + i * 256;
                int row = c >> 3;
                int kc  = (c & 7) ^ (row & 7);
                const float* pa = A + (size_t)row * C_DIM + k0 + kc * 8;
                const float* pb = B + (size_t)row * C_DIM + k0 + kc * 8;
                float4 a0 = ((const float4*)pa)[0], a1 = ((const float4*)pa)[1];
                float4 b0 = ((const float4*)pb)[0], b1 = ((const float4*)pb)[1];
                f16x8 ha = { (_Float16)a0.x, (_Float16)a0.y, (_Float16)a0.z, (_Float16)a0.w,
                             (_Float16)a1.x, (_Float16)a1.y, (_Float16)a1.z, (_Float16)a1.w };
                f16x8 hb = { (_Float16)b0.x, (_Float16)b0.y, (_Float16)b0.z, (_Float16)b0.w,
                             (_Float16)b1.x, (_Float16)b1.y, (_Float16)b1.z, (_Float16)b1.w };
                *(f16x8*)(As + (size_t)c * 8) = ha;
                *(f16x8*)(Bs + (size_t)c * 8) = hb;
            }
        }
        __syncthreads();

        f16x8 af[2][3], bf[2][3];
#pragma unroll
        for (int m = 0; m < 3; ++m) {
            int row = wr * 48 + m * 16 + r16;
#pragma unroll
            for (int ks = 0; ks < 2; ++ks)
                af[ks][m] = *(const f16x8*)(As + row * 64 + (((ks * 4 + q) ^ (row & 7)) * 8));
        }
#pragma unroll
        for (int nn = 0; nn < 3; ++nn) {
            int row = wc * 48 + nn * 16 + r16;
#pragma unroll
            for (int ks = 0; ks < 2; ++ks)
                bf[ks][nn] = *(const f16x8*)(Bs + row * 64 + (((ks * 4 + q) ^ (row & 7)) * 8));
        }
#pragma unroll
        for (int ks = 0; ks < 2; ++ks)
#pragma unroll
            for (int m = 0; m < 3; ++m)
#pragma unroll
                for (int nn = 0; nn < 3; ++nn)
                    acc[m][nn] = __builtin_amdgcn_mfma_f32_16x16x32_f16(af[ks][m], bf[ks][nn], acc[m][nn], 0, 0, 0);
    }

    const float SIM_SCALE = 0.0390625f;  // (1/sqrt(C))^2 / TEMPERATURE

    if constexpr (!FINAL) {
        // Pass A: per-block row/col partial sums of e = exp(sim) -> partA slots
        float* redR = (float*)redbuf;            // [2][96]
        float* redC = (float*)(redbuf + 768);    // [2][96]
        float cp[3] = {0.f, 0.f, 0.f};
#pragma unroll
        for (int m = 0; m < 3; ++m) {
#pragma unroll
            for (int reg = 0; reg < 4; ++reg) {
                float rsum = 0.f;
#pragma unroll
                for (int nn = 0; nn < 3; ++nn) {
                    float e = __expf(acc[m][nn][reg] * SIM_SCALE);
                    rsum += e;
                    cp[nn] += e;
                }
                rsum += __shfl_xor(rsum, 1);
                rsum += __shfl_xor(rsum, 2);
                rsum += __shfl_xor(rsum, 4);
                rsum += __shfl_xor(rsum, 8);
                if (r16 == 0)
                    redR[wc * 96 + wr * 48 + m * 16 + q * 4 + reg] = rsum;
            }
        }
#pragma unroll
        for (int nn = 0; nn < 3; ++nn) {
            float v = cp[nn];
            v += __shfl_xor(v, 16);
            v += __shfl_xor(v, 32);
            if (q == 0)
                redC[wr * 96 + wc * 48 + nn * 16 + r16] = v;
        }
        __syncthreads();
        if (tid < 96) {
            partA[(size_t)tx * 9600 + n * L_DIM + l0 + tid] = redR[tid] + redR[96 + tid];
        } else if (tid < 192) {
            int c = tid - 96;
            partA[(size_t)(50 + ty) * 9600 + n * L_DIM + s0 + c] = redC[c] + redC[96 + c];
        }
    } else {
        // Pass B: conf = exp(2*sim)*invR*invC -> write; per-block best stores
        unsigned long long* redRB = (unsigned long long*)redbuf;   // [2][96]
        unsigned* redCB = (unsigned*)(redbuf + 1536);              // [2][96]
        const size_t base = (size_t)n * L_DIM * L_DIM;
        float ivC[3];
#pragma unroll
        for (int nn = 0; nn < 3; ++nn)
            ivC[nn] = invsum[9600 + n * L_DIM + s0 + wc * 48 + nn * 16 + r16];
        float cmx[3] = {0.f, 0.f, 0.f};
#pragma unroll
        for (int m = 0; m < 3; ++m) {
#pragma unroll
            for (int reg = 0; reg < 4; ++reg) {
                const int grow = l0 + wr * 48 + m * 16 + q * 4 + reg;
                const float ivR = invsum[n * L_DIM + grow];
                const size_t rowoff = base + (size_t)grow * L_DIM;
                float bv = -1.f; int bc = 0;
#pragma unroll
                for (int nn = 0; nn < 3; ++nn) {
                    const int gcol = s0 + wc * 48 + nn * 16 + r16;
                    float cf = __expf(acc[m][nn][reg] * (2.0f * SIM_SCALE)) * ivR * ivC[nn];
                    conf[rowoff + gcol] = cf;
                    cmx[nn] = fmaxf(cmx[nn], cf);
                    if (cf > bv) { bv = cf; bc = gcol; }
                }
                unsigned long long pack =
                    ((unsigned long long)__float_as_uint(bv) << 32) |
                    (unsigned long long)(0xFFFFFFFFu - (unsigned)bc);
#pragma unroll
                for (int d = 1; d < 16; d <<= 1) {
                    unsigned long long o = __shfl_xor(pack, d);
                    if (o > pack) pack = o;
                }
                if (r16 == 0)
                    redRB[wc * 96 + wr * 48 + m * 16 + q * 4 + reg] = pack;
            }
        }
#pragma unroll
        for (int nn = 0; nn < 3; ++nn) {
            float v = cmx[nn];
            v = fmaxf(v, __shfl_xor(v, 16));
            v = fmaxf(v, __shfl_xor(v, 32));
            if (q == 0)
                redCB[wr * 96 + wc * 48 + nn * 16 + r16] = __float_as_uint(v);
        }
        __syncthreads();
        if (tid < 96) {
            unsigned long long p0 = redRB[tid], p1 = redRB[96 + tid];
            rowbest[(size_t)tx * 9600 + n * L_DIM + l0 + tid] = (p0 > p1) ? p0 : p1;
        } else if (tid < 192) {
            int c = tid - 96;
            colbest[(size_t)ty * 9600 + n * L_DIM + s0 + c] = max(redCB[c], redCB[96 + c]);
        }
    }
}

__global__ __launch_bounds__(256) void k_match(const unsigned long long* __restrict__ rowbest,
                                               const unsigned* __restrict__ colmaxF,
                                               float* __restrict__ out) {
    int i = blockIdx.x * 256 + threadIdx.x;
    if (i >= 2 * L_DIM) return;
    unsigned long long p = 0ull;
#pragma unroll 10
    for (int k = 0; k < 50; ++k) {
        unsigned long long o = rowbest[(size_t)k * 9600 + i];
        if (o > p) p = o;
    }
    int n = i / L_DIM, l = i % L_DIM;
    float v = __uint_as_float((unsigned)(p >> 32));
    int cand = (int)(0xFFFFFFFFu - (unsigned)(p & 0xFFFFFFFFull));
    if (cand < 0 || cand >= L_DIM) cand = 0;
    int h0 = l / 80, w0 = l % 80;
    int h1 = cand / 80, w1 = cand % 80;
    bool bm0 = (h0 >= 2) && (h0 < 58) && (w0 >= 2) && (w0 < 78);
    bool bm1 = (h1 >= 2) && (h1 < 58) && (w1 >= 2) && (w1 < 78);
    float cm = __uint_as_float(colmaxF[n * L_DIM + cand]);
    bool mask = (v > 0.2f) && bm0 && bm1 && (v == cm);
    out[CONF_ELEMS + i]         = mask ? 1.0f : 0.0f;        // mask_v
    out[CONF_ELEMS + 9600 + i]  = mask ? (float)cand : 0.0f; // j_ids
    out[CONF_ELEMS + 19200 + i] = mask ? v : 0.0f;           // mconf
}

extern "C" void kernel_launch(void* const* d_in, const int* in_sizes, int n_in,
                              void* d_out, int out_size, void* d_ws, size_t ws_size,
                              hipStream_t stream) {
    const float* f0 = (const float*)d_in[0];
    const float* f1 = (const float*)d_in[1];
    float* out = (float*)d_out;

    float* invsum = (float*)d_ws;
    unsigned* colmaxF = (unsigned*)((char*)d_ws + 76800);
    float* partA = (float*)((char*)d_ws + 115200);
    unsigned long long* rowbest = (unsigned long long*)((char*)d_ws + 115200);
    unsigned* colbest = (unsigned*)((char*)d_ws + 3955200);
    _Float16* h0 = (_Float16*)((char*)d_ws + 5875200);
    _Float16* h1 = h0 + (size_t)2 * L_DIM * C_DIM;

    const bool usef16 = ws_size >= WS_F16_NEEDED;

    if (usef16) {
        k_cvt2<<<dim3(2400), 256, 0, stream>>>(f0, f1, h0, h1);
        k_gemm2<true, false><<<dim3(5000), 256, 0, stream>>>(
            h0, h1, out, invsum, partA, rowbest, colbest);
        k_reduceA<<<dim3(75), 256, 0, stream>>>(partA, invsum);
        k_gemm2<true, true><<<dim3(5000), 256, 0, stream>>>(
            h0, h1, out, invsum, partA, rowbest, colbest);
    } else {
        k_gemm2<false, false><<<dim3(5000), 256, 0, stream>>>(
            f0, f1, out, invsum, partA, rowbest, colbest);
        k_reduceA<<<dim3(75), 256, 0, stream>>>(partA, invsum);
        k_gemm2<false, true><<<dim3(5000), 256, 0, stream>>>(
            f0, f1, out, invsum, partA, rowbest, colbest);
    }
    k_reduceB<<<dim3(38), 256, 0, stream>>>(colbest, colmaxF);
    k_match<<<dim3(38), 256, 0, stream>>>(rowbest, colmaxF, out);
}